// Round 9
// baseline (220.092 us; speedup 1.0000x reference)
//
#include <hip/hip_runtime.h>
#include <hip/hip_fp16.h>

typedef float    f32x4 __attribute__((ext_vector_type(4)));
typedef _Float16 f16x2 __attribute__((ext_vector_type(2)));
typedef _Float16 f16x4 __attribute__((ext_vector_type(4)));
typedef _Float16 f16x8 __attribute__((ext_vector_type(8)));

#define BS 8
#define NN 2048
#define DK 128
#define DM 64
#define MIXOFF (1024 * DK)  // halfs between mix-0 and mix-1 rows of one batch
// log2(e) / sqrt(128): folds softmax temperature AND exp->exp2 conversion into Q
#define QSCALE 0.12751744116926208f

#define MFMA32(a, b, c) __builtin_amdgcn_mfma_f32_16x16x32_f16((a), (b), (c), 0, 0, 0)
#define EXP2(x) __builtin_amdgcn_exp2f(x)

__device__ __forceinline__ f16x2 pkrtz(float x, float y) {
  return __builtin_bit_cast(f16x2, __builtin_amdgcn_cvt_pkrtz(x, y));
}

// async global->LDS DMA, 16B per lane; no VGPR transit (allocator-proof)
__device__ __forceinline__ void load_lds16(const _Float16* g, _Float16* l) {
  __builtin_amdgcn_global_load_lds(
      (const __attribute__((address_space(1))) void*)(uintptr_t)g,
      (__attribute__((address_space(3))) void*)(uint32_t)(uintptr_t)l, 16, 0, 0);
}

// ---- fused prep: K f32->f16 (512 blk), V transpose 64x64 (512 blk), q-mean (64 blk) ----
__global__ void prep_k(const float* __restrict__ kt, _Float16* __restrict__ kh,
                       const float* __restrict__ vt, _Float16* __restrict__ vT,
                       const float* __restrict__ qt, float* __restrict__ partial) {
  __shared__ float tile[64][65];
  __shared__ float red[256];
  int blk = blockIdx.x;
  int t = threadIdx.x;
  if (blk < 512) {
    size_t base = (size_t)blk * 4096;
#pragma unroll
    for (int j = 0; j < 4; ++j) {
      size_t i = base + j * 1024 + t * 4;
      f32x4 v = *(const f32x4*)(kt + i);
      f16x4 h;
      h[0] = (_Float16)v[0]; h[1] = (_Float16)v[1];
      h[2] = (_Float16)v[2]; h[3] = (_Float16)v[3];
      *(f16x4*)(kh + i) = h;
    }
  } else if (blk < 1024) {
    int i2 = blk - 512;
    int b = i2 >> 6;
    int rem = i2 & 63;
    int j0 = (rem & 31) * 64;   // key tile
    int c0 = (rem >> 5) * 64;   // channel tile
    int tx = t & 63, ty = t >> 6;
    const float* src = vt + ((size_t)b * NN + j0) * DK + c0;
#pragma unroll
    for (int rr = 0; rr < 16; ++rr) {
      int row = ty * 16 + rr;
      tile[row][tx] = src[(size_t)row * DK + tx];
    }
    __syncthreads();
    _Float16* dst = vT + ((size_t)b * DK + c0) * NN + j0;
    int chl = t >> 4;
    int k4 = (t & 15) * 4;
#pragma unroll
    for (int r2 = 0; r2 < 4; ++r2) {
      int ch = r2 * 16 + chl;
      f16x4 h;
      h[0] = (_Float16)tile[k4 + 0][ch]; h[1] = (_Float16)tile[k4 + 1][ch];
      h[2] = (_Float16)tile[k4 + 2][ch]; h[3] = (_Float16)tile[k4 + 3][ch];
      *(f16x4*)(dst + (size_t)ch * NN + k4) = h;
    }
  } else {
    int i = blk - 1024;
    int b = i >> 3, seg = i & 7;
    int c = t & 127, h = t >> 7;
    const float* p = qt + ((size_t)b * NN + seg * 256 + h * 128) * DK + c;
    float s = 0.f;
#pragma unroll 8
    for (int n = 0; n < 128; ++n) s += p[(size_t)n * DK];
    red[t] = s;
    __syncthreads();
    if (t < 128) partial[(size_t)i * 128 + t] = red[t] + red[t + 128];
  }
}

// Stage one 32-key K tile, both mixes (8KB) into buffer BUF. 512 16B units,
// one per thread. Same verified K unit map/swizzle as R6/R8. V is NOT staged:
// it is read straight from global (L1-resident) to keep it off the LDS port.
#define STAGE(BUF, S) load_lds16(khg + gKst + (S) * 2048, stg + (BUF) * 4096 + t * 8)

// ---------------- main: mixture flash attention -------------------------------
// grid 256 x 512thr (1 blk/CU, 2 waves/SIMD): b=blk&7, qb=blk>>3 (64 q/block).
// Wave = (mix m, q-tile u); all 8 waves compute every step (R8 structure, 46us).
// R8 was LDS-read-port bound: 96KB/CU-step (V duplicated x8). Now V fragments
// load DIRECTLY from global vT (same 8KB read by all waves -> L1-resident; L1
// path runs in parallel with the LDS port); LDS stages K only (8KB/step dbuf).
// LDS reads 96->32KB/step; V bank conflicts vanish; barrier drain halves.
// Verified layouts: S^T via mfma(K-perm rows, Q^T); P^T D-frag == x32 B-operand;
// V^T f16x8 A-frags (ch=cc*16+l16, keys=quad*8..); l via lane sums + 2 shfl_xor.
__global__ __launch_bounds__(512, 2) void attn_k(const float* __restrict__ qt,
                                                 const _Float16* __restrict__ khg,
                                                 const _Float16* __restrict__ vTg,
                                                 const float* __restrict__ kern,
                                                 const float* __restrict__ partial,
                                                 float* __restrict__ out) {
  __shared__ __align__(16) char smem[40960];
  _Float16* stg = (_Float16*)smem;  // [2][4096] halfs = 2 x 8KB staging
  const int b = blockIdx.x & 7;
  const int qb = blockIdx.x >> 3;
  const int t = threadIdx.x;
  const int wv = t >> 6;
  const int m = wv >> 2;       // mixture handled by this wave
  const int u = wv & 3;        // 16-query tile within block
  const int lane = t & 63;
  const int quad = lane >> 4, l16 = lane & 15;
  const int perm = ((l16 >> 2) << 3) | (l16 & 3);
  const int bq = b * (NN * DK);
  const int bV = b * (DK * NN);

  // Q fragments for this wave's (m, u): f32 load + scale + pack in-register
  f16x8 qf[2];
#pragma unroll
  for (int c = 0; c < 2; ++c) {
    const float* qp_ = qt + bq + m * MIXOFF +
                       (qb * 64 + u * 16 + l16) * DM + quad * 8 + c * 32;
    f32x4 v0 = *(const f32x4*)qp_;
    f32x4 v1 = *(const f32x4*)(qp_ + 4);
    union { f16x8 v; f16x2 h[4]; } w;
    w.h[0] = pkrtz(v0[0] * QSCALE, v0[1] * QSCALE);
    w.h[1] = pkrtz(v0[2] * QSCALE, v0[3] * QSCALE);
    w.h[2] = pkrtz(v1[0] * QSCALE, v1[1] * QSCALE);
    w.h[3] = pkrtz(v1[2] * QSCALE, v1[3] * QSCALE);
    qf[c] = w.v;
  }

  // staging offsets (halfs): thread t stages K unit t (verified R6 map)
  const int mixu = t >> 8;
  const int qq8 = t & 255;
  const int rK = qq8 >> 3;
  const int uuK = (qq8 & 7) ^ ((rK & 3) ^ ((rK >> 3) << 1));
  const int gKst = bq + mixu * MIXOFF + rK * 64 + uuK * 8;

  // LDS K read offsets (halfs), matching the unit map (verified R6)
  const int gK = (l16 & 3) ^ ((l16 >> 2) << 1);
  const int kA = (quad ^ gK) * 8;
  const int kB = ((quad + 4) ^ gK) * 8;
  const int kr0 = m * 2048 + perm * 64;
  const int kr1 = m * 2048 + (perm + 4) * 64;

  // V global base: channel = cc*16 + l16, keys = s*32 + quad*8 .. +8
  const _Float16* vp0 = vTg + bV + (size_t)l16 * NN + quad * 8;

  const f32x4 z = {0.f, 0.f, 0.f, 0.f};
  f32x4 acc[8];
  float lsum = 0.f;
#pragma unroll
  for (int cc = 0; cc < 8; ++cc) acc[cc] = z;

  STAGE(0, 0);
  int buf = 0;
  for (int s = 0; s < 64; ++s) {
    __syncthreads();  // K tile s landed; reads of buf^1 (step s-1) done
    if (s + 1 < 64) STAGE(buf ^ 1, s + 1);
    // V: straight from global (L1 after first wave touches it) — issued first
    // so the vmcnt latency hides under the K ds_read -> QK -> exp chain.
    f16x8 vf[8];
#pragma unroll
    for (int cc = 0; cc < 8; ++cc)
      vf[cc] = *(const f16x8*)(vp0 + (size_t)(cc * 16) * NN + s * 32);
    const _Float16* sb_ = stg + buf * 4096;
    f16x8 kf0 = *(const f16x8*)(sb_ + kr0 + kA);
    f16x8 kf1 = *(const f16x8*)(sb_ + kr0 + kB);
    f16x8 kf2 = *(const f16x8*)(sb_ + kr1 + kA);
    f16x8 kf3 = *(const f16x8*)(sb_ + kr1 + kB);
    f32x4 s0 = MFMA32(kf1, qf[1], MFMA32(kf0, qf[0], z));
    f32x4 s1 = MFMA32(kf3, qf[1], MFMA32(kf2, qf[0], z));
    float e0 = EXP2(s0[0]), e1 = EXP2(s0[1]), e2 = EXP2(s0[2]), e3 = EXP2(s0[3]);
    float e4 = EXP2(s1[0]), e5 = EXP2(s1[1]), e6 = EXP2(s1[2]), e7 = EXP2(s1[3]);
    lsum += ((e0 + e1) + (e2 + e3)) + ((e4 + e5) + (e6 + e7));
    union { f16x8 v; f16x2 h[4]; } w;
    w.h[0] = pkrtz(e0, e1); w.h[1] = pkrtz(e2, e3);
    w.h[2] = pkrtz(e4, e5); w.h[3] = pkrtz(e6, e7);
#pragma unroll
    for (int cc = 0; cc < 8; ++cc) acc[cc] = MFMA32(vf[cc], w.v, acc[cc]);
    buf ^= 1;
  }
  __syncthreads();  // all tile reads done; epilogue overlays staging LDS

  // ---- epilogue ----
  float* obuf = (float*)smem;                  // [64][132] floats (33792 B)
  float* barL = (float*)(smem + 33792);        // [8][128]
  float* lgp = (float*)(smem + 37888);
  float* exq = (float*)(smem + 37952);
  float* prp = (float*)(smem + 38016);

  // prior softmax (redundant per block)
  for (int e = t; e < 1024; e += 512) {
    int bb = e >> 7, c = e & 127;
    float ss = 0.f;
#pragma unroll
    for (int seg = 0; seg < 8; ++seg) ss += partial[(size_t)(bb * 8 + seg) * 128 + c];
    barL[e] = ss * (1.0f / 2048.0f);
  }
  __syncthreads();
  if (t < 16) {
    int mm = t >> 3, bb = t & 7;
    float ss = 0.f;
    for (int c = 0; c < DK; ++c) ss += kern[mm * DK + c] * barL[bb * 128 + c];
    lgp[t] = ss;
  }
  __syncthreads();
  if (t < 16) {
    int mm = t >> 3;
    float mx = lgp[mm * 8];
    for (int i = 1; i < 8; ++i) mx = fmaxf(mx, lgp[mm * 8 + i]);
    exq[t] = __expf(lgp[t] - mx);
  }
  __syncthreads();
  if (t < 16) {
    int mm = t >> 3;
    float sm = 0.f;
    for (int i = 0; i < 8; ++i) sm += exq[mm * 8 + i];
    prp[t] = exq[t] / sm;  // flat[m*8+b]; read as [b*2+m] (TF reshape quirk)
  }
  __syncthreads();

  // l for this lane's query: sum partials across quads (lanes xor 16, 32)
  lsum += __shfl_xor(lsum, 16);
  lsum += __shfl_xor(lsum, 32);
  const float r_ = prp[b * 2 + m] / lsum;

  const int orow = (u * 16 + l16) * 132;
  if (m == 0) {
#pragma unroll
    for (int cc = 0; cc < 8; ++cc) {
      f32x4 o;
#pragma unroll
      for (int e = 0; e < 4; ++e) o[e] = acc[cc][e] * r_;
      *(f32x4*)&obuf[orow + cc * 16 + quad * 4] = o;
    }
  }
  __syncthreads();
  if (m == 1) {
#pragma unroll
    for (int cc = 0; cc < 8; ++cc) {
      f32x4 o = *(const f32x4*)&obuf[orow + cc * 16 + quad * 4];
#pragma unroll
      for (int e = 0; e < 4; ++e) o[e] += acc[cc][e] * r_;
      *(f32x4*)&obuf[orow + cc * 16 + quad * 4] = o;
    }
  }
  __syncthreads();
  const int row = t >> 3;
  const int cb = (t & 7) * 16;
  float* op = out + ((size_t)b * NN + qb * 64 + row) * DK + cb;
#pragma unroll
  for (int g = 0; g < 4; ++g)
    *(f32x4*)(op + g * 4) = *(const f32x4*)&obuf[row * 132 + cb + g * 4];
}

extern "C" void kernel_launch(void* const* d_in, const int* in_sizes, int n_in,
                              void* d_out, int out_size, void* d_ws, size_t ws_size,
                              hipStream_t stream) {
  const float* qt = (const float*)d_in[0];
  const float* kt = (const float*)d_in[1];
  const float* vt = (const float*)d_in[2];
  const float* kern = (const float*)d_in[3];
  float* out = (float*)d_out;

  char* ws = (char*)d_ws;
  float* partial = (float*)ws;               // 64*128 floats (32 KB)
  _Float16* khp = (_Float16*)(ws + 65536);   // 2M halfs (4 MB)
  _Float16* vTp = khp + (size_t)BS * NN * DK;

  prep_k<<<dim3(1088), dim3(256), 0, stream>>>(kt, khp, vt, vTp, qt, partial);
  attn_k<<<dim3(256), dim3(512), 0, stream>>>(qt, khp, vTp, kern, partial, out);
}

// Round 10
// 216.961 us; speedup vs baseline: 1.0144x; 1.0144x over previous
//
#include <hip/hip_runtime.h>
#include <hip/hip_fp16.h>

typedef float    f32x4 __attribute__((ext_vector_type(4)));
typedef _Float16 f16x2 __attribute__((ext_vector_type(2)));
typedef _Float16 f16x4 __attribute__((ext_vector_type(4)));
typedef _Float16 f16x8 __attribute__((ext_vector_type(8)));

#define BS 8
#define NN 2048
#define DK 128
#define DM 64
#define MIXOFF (1024 * DK)  // halfs between mix-0 and mix-1 rows of one batch
// log2(e) / sqrt(128): folds softmax temperature AND exp->exp2 conversion into Q
#define QSCALE 0.12751744116926208f

#define MFMA32(a, b, c) __builtin_amdgcn_mfma_f32_16x16x32_f16((a), (b), (c), 0, 0, 0)
#define EXP2(x) __builtin_amdgcn_exp2f(x)

__device__ __forceinline__ f16x2 pkrtz(float x, float y) {
  return __builtin_bit_cast(f16x2, __builtin_amdgcn_cvt_pkrtz(x, y));
}

// async global->LDS DMA, 16B per lane; no VGPR transit (allocator-proof)
__device__ __forceinline__ void load_lds16(const _Float16* g, _Float16* l) {
  __builtin_amdgcn_global_load_lds(
      (const __attribute__((address_space(1))) void*)(uintptr_t)g,
      (__attribute__((address_space(3))) void*)(uint32_t)(uintptr_t)l, 16, 0, 0);
}

// ---- fused prep: K f32->f16 (512 blk), V transpose 64x64 (512 blk), q-mean (64 blk) ----
__global__ void prep_k(const float* __restrict__ kt, _Float16* __restrict__ kh,
                       const float* __restrict__ vt, _Float16* __restrict__ vT,
                       const float* __restrict__ qt, float* __restrict__ partial) {
  __shared__ float tile[64][65];
  __shared__ float red[256];
  int blk = blockIdx.x;
  int t = threadIdx.x;
  if (blk < 512) {
    size_t base = (size_t)blk * 4096;
#pragma unroll
    for (int j = 0; j < 4; ++j) {
      size_t i = base + j * 1024 + t * 4;
      f32x4 v = *(const f32x4*)(kt + i);
      f16x4 h;
      h[0] = (_Float16)v[0]; h[1] = (_Float16)v[1];
      h[2] = (_Float16)v[2]; h[3] = (_Float16)v[3];
      *(f16x4*)(kh + i) = h;
    }
  } else if (blk < 1024) {
    int i2 = blk - 512;
    int b = i2 >> 6;
    int rem = i2 & 63;
    int j0 = (rem & 31) * 64;   // key tile
    int c0 = (rem >> 5) * 64;   // channel tile
    int tx = t & 63, ty = t >> 6;
    const float* src = vt + ((size_t)b * NN + j0) * DK + c0;
#pragma unroll
    for (int rr = 0; rr < 16; ++rr) {
      int row = ty * 16 + rr;
      tile[row][tx] = src[(size_t)row * DK + tx];
    }
    __syncthreads();
    _Float16* dst = vT + ((size_t)b * DK + c0) * NN + j0;
    int chl = t >> 4;
    int k4 = (t & 15) * 4;
#pragma unroll
    for (int r2 = 0; r2 < 4; ++r2) {
      int ch = r2 * 16 + chl;
      f16x4 h;
      h[0] = (_Float16)tile[k4 + 0][ch]; h[1] = (_Float16)tile[k4 + 1][ch];
      h[2] = (_Float16)tile[k4 + 2][ch]; h[3] = (_Float16)tile[k4 + 3][ch];
      *(f16x4*)(dst + (size_t)ch * NN + k4) = h;
    }
  } else {
    int i = blk - 1024;
    int b = i >> 3, seg = i & 7;
    int c = t & 127, h = t >> 7;
    const float* p = qt + ((size_t)b * NN + seg * 256 + h * 128) * DK + c;
    float s = 0.f;
#pragma unroll 8
    for (int n = 0; n < 128; ++n) s += p[(size_t)n * DK];
    red[t] = s;
    __syncthreads();
    if (t < 128) partial[(size_t)i * 128 + t] = red[t] + red[t + 128];
  }
}

// Stage one 32-key K tile, both mixes (8KB) into buffer BUF. 512 16B units,
// one per thread. Verified K unit map/swizzle (R6/R8). V is NOT staged.
#define STAGE(BUF, S) load_lds16(khg + gKst + (S) * 2048, stg + (BUF) * 4096 + t * 8)

// V register prefetch for step S into fixed array VF (constant indices: SROA-safe).
// Consumer is after the NEXT barrier, whose built-in vmcnt(0) drain covers it ->
// PV needs no in-step VMEM wait (R9's bug: V waits coupled to staging vmcnt).
#define LDVG(VF, S) do {                                                   \
    _Pragma("unroll")                                                      \
    for (int cc = 0; cc < 8; ++cc)                                         \
      VF[cc] = *(const f16x8*)(vp0 + (size_t)(cc * 16) * NN + (S) * 32);   \
  } while (0)

// One 32-key step: K from LDS buffer BUF, V from register array VF.
#define CSTEP(BUF, VF) do {                                                \
    const _Float16* sb_ = stg + (BUF) * 4096;                              \
    f16x8 kf0 = *(const f16x8*)(sb_ + kr0 + kA);                           \
    f16x8 kf1 = *(const f16x8*)(sb_ + kr0 + kB);                           \
    f16x8 kf2 = *(const f16x8*)(sb_ + kr1 + kA);                           \
    f16x8 kf3 = *(const f16x8*)(sb_ + kr1 + kB);                           \
    f32x4 s0 = MFMA32(kf1, qf[1], MFMA32(kf0, qf[0], z));                  \
    f32x4 s1 = MFMA32(kf3, qf[1], MFMA32(kf2, qf[0], z));                  \
    float e0 = EXP2(s0[0]), e1 = EXP2(s0[1]), e2 = EXP2(s0[2]), e3 = EXP2(s0[3]); \
    float e4 = EXP2(s1[0]), e5 = EXP2(s1[1]), e6 = EXP2(s1[2]), e7 = EXP2(s1[3]); \
    lsum += ((e0 + e1) + (e2 + e3)) + ((e4 + e5) + (e6 + e7));             \
    union { f16x8 v; f16x2 h[4]; } w;                                      \
    w.h[0] = pkrtz(e0, e1); w.h[1] = pkrtz(e2, e3);                        \
    w.h[2] = pkrtz(e4, e5); w.h[3] = pkrtz(e6, e7);                        \
    _Pragma("unroll")                                                      \
    for (int cc = 0; cc < 8; ++cc) acc[cc] = MFMA32(VF[cc], w.v, acc[cc]); \
  } while (0)

// ---------------- main: mixture flash attention -------------------------------
// grid 256 x 512thr (1 blk/CU, 2 waves/SIMD): b=blk&7, qb=blk>>3 (64 q/block).
// Wave = (mix m, q-tile u); all 8 waves compute every step (R8 structure).
// K staged to LDS (8KB/step dbuf, verified swizzles); V register-double-buffered
// from global (L1-resident, off the LDS port). V prefetch for s+1 issues during
// step s; the next barrier's vmcnt(0) drain (already required for staging)
// completes it -> PV has NO VMEM wait; K path waits lgkmcnt only.
// l via lane sums + 2 shfl_xor; mix merge in epilogue (m0 writes, m1 adds).
__global__ __launch_bounds__(512, 2) void attn_k(const float* __restrict__ qt,
                                                 const _Float16* __restrict__ khg,
                                                 const _Float16* __restrict__ vTg,
                                                 const float* __restrict__ kern,
                                                 const float* __restrict__ partial,
                                                 float* __restrict__ out) {
  __shared__ __align__(16) char smem[40960];
  _Float16* stg = (_Float16*)smem;  // [2][4096] halfs = 2 x 8KB staging
  const int b = blockIdx.x & 7;
  const int qb = blockIdx.x >> 3;
  const int t = threadIdx.x;
  const int wv = t >> 6;
  const int m = wv >> 2;       // mixture handled by this wave
  const int u = wv & 3;        // 16-query tile within block
  const int lane = t & 63;
  const int quad = lane >> 4, l16 = lane & 15;
  const int perm = ((l16 >> 2) << 3) | (l16 & 3);
  const int bq = b * (NN * DK);
  const int bV = b * (DK * NN);

  // Q fragments for this wave's (m, u): f32 load + scale + pack in-register
  f16x8 qf[2];
#pragma unroll
  for (int c = 0; c < 2; ++c) {
    const float* qp_ = qt + bq + m * MIXOFF +
                       (qb * 64 + u * 16 + l16) * DM + quad * 8 + c * 32;
    f32x4 v0 = *(const f32x4*)qp_;
    f32x4 v1 = *(const f32x4*)(qp_ + 4);
    union { f16x8 v; f16x2 h[4]; } w;
    w.h[0] = pkrtz(v0[0] * QSCALE, v0[1] * QSCALE);
    w.h[1] = pkrtz(v0[2] * QSCALE, v0[3] * QSCALE);
    w.h[2] = pkrtz(v1[0] * QSCALE, v1[1] * QSCALE);
    w.h[3] = pkrtz(v1[2] * QSCALE, v1[3] * QSCALE);
    qf[c] = w.v;
  }

  // staging offsets (halfs): thread t stages K unit t (verified R6 map)
  const int mixu = t >> 8;
  const int qq8 = t & 255;
  const int rK = qq8 >> 3;
  const int uuK = (qq8 & 7) ^ ((rK & 3) ^ ((rK >> 3) << 1));
  const int gKst = bq + mixu * MIXOFF + rK * 64 + uuK * 8;

  // LDS K read offsets (halfs), matching the unit map (verified R6)
  const int gK = (l16 & 3) ^ ((l16 >> 2) << 1);
  const int kA = (quad ^ gK) * 8;
  const int kB = ((quad + 4) ^ gK) * 8;
  const int kr0 = m * 2048 + perm * 64;
  const int kr1 = m * 2048 + (perm + 4) * 64;

  // V global base: channel = cc*16 + l16, keys = s*32 + quad*8 .. +8
  const _Float16* vp0 = vTg + bV + (size_t)l16 * NN + quad * 8;

  const f32x4 z = {0.f, 0.f, 0.f, 0.f};
  f32x4 acc[8];
  float lsum = 0.f;
#pragma unroll
  for (int cc = 0; cc < 8; ++cc) acc[cc] = z;

  f16x8 va[8], vb[8];
  LDVG(va, 0);   // V for step 0 (completes at first barrier's drain)
  STAGE(0, 0);
  for (int s = 0; s < 64; s += 2) {
    __syncthreads();  // K tile s landed; va holds V(s); buf1 reads (s-1) done
    STAGE(1, s + 1);
    LDVG(vb, s + 1);
    CSTEP(0, va);
    __syncthreads();  // K tile s+1 landed; vb holds V(s+1); buf0 reads done
    if (s + 2 < 64) STAGE(0, s + 2);
    LDVG(va, (s + 2) & 63);  // wrap on last pair: harmless warm reload
    CSTEP(1, vb);
  }
  __syncthreads();  // all tile reads done; epilogue overlays staging LDS

  // ---- epilogue ----
  float* obuf = (float*)smem;                  // [64][132] floats (33792 B)
  float* barL = (float*)(smem + 33792);        // [8][128]
  float* lgp = (float*)(smem + 37888);
  float* exq = (float*)(smem + 37952);
  float* prp = (float*)(smem + 38016);

  // prior softmax (redundant per block)
  for (int e = t; e < 1024; e += 512) {
    int bb = e >> 7, c = e & 127;
    float ss = 0.f;
#pragma unroll
    for (int seg = 0; seg < 8; ++seg) ss += partial[(size_t)(bb * 8 + seg) * 128 + c];
    barL[e] = ss * (1.0f / 2048.0f);
  }
  __syncthreads();
  if (t < 16) {
    int mm = t >> 3, bb = t & 7;
    float ss = 0.f;
    for (int c = 0; c < DK; ++c) ss += kern[mm * DK + c] * barL[bb * 128 + c];
    lgp[t] = ss;
  }
  __syncthreads();
  if (t < 16) {
    int mm = t >> 3;
    float mx = lgp[mm * 8];
    for (int i = 1; i < 8; ++i) mx = fmaxf(mx, lgp[mm * 8 + i]);
    exq[t] = __expf(lgp[t] - mx);
  }
  __syncthreads();
  if (t < 16) {
    int mm = t >> 3;
    float sm = 0.f;
    for (int i = 0; i < 8; ++i) sm += exq[mm * 8 + i];
    prp[t] = exq[t] / sm;  // flat[m*8+b]; read as [b*2+m] (TF reshape quirk)
  }
  __syncthreads();

  // l for this lane's query: sum partials across quads (lanes xor 16, 32)
  lsum += __shfl_xor(lsum, 16);
  lsum += __shfl_xor(lsum, 32);
  const float r_ = prp[b * 2 + m] / lsum;

  const int orow = (u * 16 + l16) * 132;
  if (m == 0) {
#pragma unroll
    for (int cc = 0; cc < 8; ++cc) {
      f32x4 o;
#pragma unroll
      for (int e = 0; e < 4; ++e) o[e] = acc[cc][e] * r_;
      *(f32x4*)&obuf[orow + cc * 16 + quad * 4] = o;
    }
  }
  __syncthreads();
  if (m == 1) {
#pragma unroll
    for (int cc = 0; cc < 8; ++cc) {
      f32x4 o = *(const f32x4*)&obuf[orow + cc * 16 + quad * 4];
#pragma unroll
      for (int e = 0; e < 4; ++e) o[e] += acc[cc][e] * r_;
      *(f32x4*)&obuf[orow + cc * 16 + quad * 4] = o;
    }
  }
  __syncthreads();
  const int row = t >> 3;
  const int cb = (t & 7) * 16;
  float* op = out + ((size_t)b * NN + qb * 64 + row) * DK + cb;
#pragma unroll
  for (int g = 0; g < 4; ++g)
    *(f32x4*)(op + g * 4) = *(const f32x4*)&obuf[row * 132 + cb + g * 4];
}

extern "C" void kernel_launch(void* const* d_in, const int* in_sizes, int n_in,
                              void* d_out, int out_size, void* d_ws, size_t ws_size,
                              hipStream_t stream) {
  const float* qt = (const float*)d_in[0];
  const float* kt = (const float*)d_in[1];
  const float* vt = (const float*)d_in[2];
  const float* kern = (const float*)d_in[3];
  float* out = (float*)d_out;

  char* ws = (char*)d_ws;
  float* partial = (float*)ws;               // 64*128 floats (32 KB)
  _Float16* khp = (_Float16*)(ws + 65536);   // 2M halfs (4 MB)
  _Float16* vTp = khp + (size_t)BS * NN * DK;

  prep_k<<<dim3(1088), dim3(256), 0, stream>>>(kt, khp, vt, vTp, qt, partial);
  attn_k<<<dim3(256), dim3(512), 0, stream>>>(qt, khp, vTp, kern, partial, out);
}

// Round 11
// 189.880 us; speedup vs baseline: 1.1591x; 1.1426x over previous
//
#include <hip/hip_runtime.h>
#include <hip/hip_fp16.h>

typedef float    f32x4 __attribute__((ext_vector_type(4)));
typedef _Float16 f16x2 __attribute__((ext_vector_type(2)));
typedef _Float16 f16x4 __attribute__((ext_vector_type(4)));
typedef _Float16 f16x8 __attribute__((ext_vector_type(8)));

#define BS 8
#define NN 2048
#define DK 128
#define DM 64
#define MIXOFF (1024 * DK)  // halfs between mix-0 and mix-1 rows of one batch
// log2(e) / sqrt(128): folds softmax temperature AND exp->exp2 conversion into Q
#define QSCALE 0.12751744116926208f
#define SLOTF 33024  // floats per (pair,kh) partial slot: O[2][128][128] + l[2][128]

#define MFMA32(a, b, c) __builtin_amdgcn_mfma_f32_16x16x32_f16((a), (b), (c), 0, 0, 0)
#define EXP2(x) __builtin_amdgcn_exp2f(x)

__device__ __forceinline__ f16x2 pkrtz(float x, float y) {
  return __builtin_bit_cast(f16x2, __builtin_amdgcn_cvt_pkrtz(x, y));
}

// async global->LDS DMA, 16B per lane; no VGPR transit (allocator-proof)
__device__ __forceinline__ void load_lds16(const _Float16* g, _Float16* l) {
  __builtin_amdgcn_global_load_lds(
      (const __attribute__((address_space(1))) void*)(uintptr_t)g,
      (__attribute__((address_space(3))) void*)(uint32_t)(uintptr_t)l, 16, 0, 0);
}

// ---- fused prep: K f32->f16 (512 blk), V transpose 64x64 (512 blk), q-mean (64 blk) ----
__global__ void prep_k(const float* __restrict__ kt, _Float16* __restrict__ kh,
                       const float* __restrict__ vt, _Float16* __restrict__ vT,
                       const float* __restrict__ qt, float* __restrict__ qpart) {
  __shared__ float tile[64][65];
  __shared__ float red[256];
  int blk = blockIdx.x;
  int t = threadIdx.x;
  if (blk < 512) {
    size_t base = (size_t)blk * 4096;
#pragma unroll
    for (int j = 0; j < 4; ++j) {
      size_t i = base + j * 1024 + t * 4;
      f32x4 v = *(const f32x4*)(kt + i);
      f16x4 h;
      h[0] = (_Float16)v[0]; h[1] = (_Float16)v[1];
      h[2] = (_Float16)v[2]; h[3] = (_Float16)v[3];
      *(f16x4*)(kh + i) = h;
    }
  } else if (blk < 1024) {
    int i2 = blk - 512;
    int b = i2 >> 6;
    int rem = i2 & 63;
    int j0 = (rem & 31) * 64;   // key tile
    int c0 = (rem >> 5) * 64;   // channel tile
    int tx = t & 63, ty = t >> 6;
    const float* src = vt + ((size_t)b * NN + j0) * DK + c0;
#pragma unroll
    for (int rr = 0; rr < 16; ++rr) {
      int row = ty * 16 + rr;
      tile[row][tx] = src[(size_t)row * DK + tx];
    }
    __syncthreads();
    _Float16* dst = vT + ((size_t)b * DK + c0) * NN + j0;
    int chl = t >> 4;
    int k4 = (t & 15) * 4;
#pragma unroll
    for (int r2 = 0; r2 < 4; ++r2) {
      int ch = r2 * 16 + chl;
      f16x4 h;
      h[0] = (_Float16)tile[k4 + 0][ch]; h[1] = (_Float16)tile[k4 + 1][ch];
      h[2] = (_Float16)tile[k4 + 2][ch]; h[3] = (_Float16)tile[k4 + 3][ch];
      *(f16x4*)(dst + (size_t)ch * NN + k4) = h;
    }
  } else {
    int i = blk - 1024;
    int b = i >> 3, seg = i & 7;
    int c = t & 127, h = t >> 7;
    const float* p = qt + ((size_t)b * NN + seg * 256 + h * 128) * DK + c;
    float s = 0.f;
#pragma unroll 8
    for (int n = 0; n < 128; ++n) s += p[(size_t)n * DK];
    red[t] = s;
    __syncthreads();
    if (t < 128) qpart[(size_t)i * 128 + t] = red[t] + red[t + 128];
  }
}

// Stage one 32-key tile (16KB: K both mixes 8KB + V 8KB) into buffer BUF.
// 1024 16B units, 512 threads x 2. Verified unit map/swizzles (R6/R8).
#define STAGE(BUF, S) do {                                 \
    _Float16* db_ = stg + (BUF) * 8192;                    \
    load_lds16(khg + gKst + (S) * 2048, db_ + t * 8);      \
    load_lds16(vTg + gVst + (S) * 32, db_ + 4096 + t * 8); \
  } while (0)

// ---------------- main: mixture flash attention, split-K + merge --------------
// grid 256 x 512thr (1 blk/CU): b=blk&7, qb=(blk>>3)&15, kh=blk>>7 (key half).
// Wave = (mix m, q-tile u): 32 QUERIES per wave (2 x 16q subtiles) -> K frags
// (4 ds_reads) feed 8 QK MFMAs, V frags (8 reads, shared across subtiles) feed
// 16 PV MFMAs = 2.0 MFMA per ds_read_b128 (R8 was 1.0 -> LDS-port bound).
// 1024 keys/block in 32 steps with R8's proven stage/barrier skeleton.
// Pair (kh=0,1) merge: plain-store partial O/l -> threadfence -> counter
// atomicAdd; second arriver folds partner partial into live regs, computes
// prior softmax, normalizes, stores. No spin; order-independent (G16-safe).
__global__ __launch_bounds__(512, 2) void attn_k(const float* __restrict__ qt,
                                                 const _Float16* __restrict__ khg,
                                                 const _Float16* __restrict__ vTg,
                                                 const float* __restrict__ kern,
                                                 const float* __restrict__ qpart,
                                                 float* __restrict__ slots,
                                                 int* __restrict__ counters,
                                                 float* __restrict__ out) {
  __shared__ __align__(16) char smem[40960];
  _Float16* stg = (_Float16*)smem;  // [2][8192] halfs = 2 x 16KB staging
  const int b = blockIdx.x & 7;
  const int qb = (blockIdx.x >> 3) & 15;
  const int kh = blockIdx.x >> 7;
  const int pair = blockIdx.x & 127;
  const int t = threadIdx.x;
  const int wv = t >> 6;
  const int m = wv >> 2;       // mixture handled by this wave
  const int u = wv & 3;        // 32-query tile within block
  const int lane = t & 63;
  const int quad = lane >> 4, l16 = lane & 15;
  const int perm = ((l16 >> 2) << 3) | (l16 & 3);
  const int bq = b * (NN * DK);
  const int bV = b * (DK * NN);

  // Q fragments: 2 subtiles x 2 chunks, f32 load + scale + pack in-register
  f16x8 qf[2][2];  // [su][chunk]
#pragma unroll
  for (int su = 0; su < 2; ++su)
#pragma unroll
    for (int c = 0; c < 2; ++c) {
      const float* qp_ = qt + bq + m * MIXOFF +
                         (qb * 128 + u * 32 + su * 16 + l16) * DM + quad * 8 + c * 32;
      f32x4 v0 = *(const f32x4*)qp_;
      f32x4 v1 = *(const f32x4*)(qp_ + 4);
      union { f16x8 v; f16x2 h[4]; } w;
      w.h[0] = pkrtz(v0[0] * QSCALE, v0[1] * QSCALE);
      w.h[1] = pkrtz(v0[2] * QSCALE, v0[3] * QSCALE);
      w.h[2] = pkrtz(v1[0] * QSCALE, v1[1] * QSCALE);
      w.h[3] = pkrtz(v1[2] * QSCALE, v1[3] * QSCALE);
      qf[su][c] = w.v;
    }

  // staging offsets (halfs): thread t stages K unit t and V unit t (R6 map),
  // shifted to this block's key half.
  const int mixu = t >> 8;
  const int qq8 = t & 255;
  const int rK = qq8 >> 3;
  const int uuK = (qq8 & 7) ^ ((rK & 3) ^ ((rK >> 3) << 1));
  const int chV = t >> 2;
  const int uuV = (t & 3) ^ ((chV + (chV >> 2)) & 3);
  const int gKst = bq + mixu * MIXOFF + kh * (1024 * DM) + rK * 64 + uuK * 8;
  const int gVst = bV + chV * NN + kh * 1024 + uuV * 8;

  // LDS read offsets (halfs), matching the unit map (verified R6/R8)
  const int gK = (l16 & 3) ^ ((l16 >> 2) << 1);
  const int hV = (l16 + (l16 >> 2)) & 3;
  const int kA = (quad ^ gK) * 8;
  const int kB = ((quad + 4) ^ gK) * 8;
  const int kr0 = m * 2048 + perm * 64;
  const int kr1 = m * 2048 + (perm + 4) * 64;
  const int vbase = 4096 + l16 * 32 + (quad ^ hV) * 8;

  const f32x4 z = {0.f, 0.f, 0.f, 0.f};
  f32x4 acc[2][8];  // [su][cc]
  float lsum[2] = {0.f, 0.f};
#pragma unroll
  for (int su = 0; su < 2; ++su)
#pragma unroll
    for (int cc = 0; cc < 8; ++cc) acc[su][cc] = z;

  STAGE(0, 0);
  int buf = 0;
  for (int s = 0; s < 32; ++s) {
    __syncthreads();  // tile s landed; reads of buf^1 (step s-1) done
    if (s + 1 < 32) STAGE(buf ^ 1, s + 1);
    const _Float16* sb_ = stg + buf * 8192;
    f16x8 kf0 = *(const f16x8*)(sb_ + kr0 + kA);
    f16x8 kf1 = *(const f16x8*)(sb_ + kr0 + kB);
    f16x8 kf2 = *(const f16x8*)(sb_ + kr1 + kA);
    f16x8 kf3 = *(const f16x8*)(sb_ + kr1 + kB);
    f16x8 vf[8];
#pragma unroll
    for (int cc = 0; cc < 8; ++cc) vf[cc] = *(const f16x8*)(sb_ + vbase + cc * 512);
#pragma unroll
    for (int su = 0; su < 2; ++su) {
      f32x4 s0 = MFMA32(kf1, qf[su][1], MFMA32(kf0, qf[su][0], z));
      f32x4 s1 = MFMA32(kf3, qf[su][1], MFMA32(kf2, qf[su][0], z));
      float e0 = EXP2(s0[0]), e1 = EXP2(s0[1]), e2 = EXP2(s0[2]), e3 = EXP2(s0[3]);
      float e4 = EXP2(s1[0]), e5 = EXP2(s1[1]), e6 = EXP2(s1[2]), e7 = EXP2(s1[3]);
      lsum[su] += ((e0 + e1) + (e2 + e3)) + ((e4 + e5) + (e6 + e7));
      union { f16x8 v; f16x2 h[4]; } w;
      w.h[0] = pkrtz(e0, e1); w.h[1] = pkrtz(e2, e3);
      w.h[2] = pkrtz(e4, e5); w.h[3] = pkrtz(e6, e7);
#pragma unroll
      for (int cc = 0; cc < 8; ++cc) acc[su][cc] = MFMA32(vf[cc], w.v, acc[su][cc]);
    }
    buf ^= 1;
  }

  // ---- reduce l across quads (all lanes end with the row sum) ----
#pragma unroll
  for (int su = 0; su < 2; ++su) {
    lsum[su] += __shfl_xor(lsum[su], 16);
    lsum[su] += __shfl_xor(lsum[su], 32);
  }

  // ---- store partial (own slot), signal pair counter ----
  float* slot = slots + (size_t)pair * (2 * SLOTF) + (size_t)kh * SLOTF;
#pragma unroll
  for (int su = 0; su < 2; ++su) {
    int r_ = (m * 128 + u * 32 + su * 16 + l16) * 128 + quad * 4;
#pragma unroll
    for (int cc = 0; cc < 8; ++cc)
      *(f32x4*)(slot + r_ + cc * 16) = acc[su][cc];
    if (quad == 0) slot[32768 + m * 128 + u * 32 + su * 16 + l16] = lsum[su];
  }
  __threadfence();
  int* flagp = (int*)(smem + 38912);
  if (t == 0) *flagp = atomicAdd(&counters[pair], 1);
  __syncthreads();
  if (*flagp == 0) return;  // first arriver: partner will merge
  __threadfence();          // acquire: partner's stores now visible

  // ---- winner: prior softmax (overlay LDS beyond staging region) ----
  float* obuf = (float*)smem;                  // [64][132] floats (33792 B)
  float* barL = (float*)(smem + 33792);        // [8][128]
  float* lgp = (float*)(smem + 37888);
  float* exq = (float*)(smem + 37952);
  float* prp = (float*)(smem + 38016);
  for (int e = t; e < 1024; e += 512) {
    int bb = e >> 7, c = e & 127;
    float ss = 0.f;
#pragma unroll
    for (int seg = 0; seg < 8; ++seg) ss += qpart[(size_t)(bb * 8 + seg) * 128 + c];
    barL[e] = ss * (1.0f / 2048.0f);
  }
  __syncthreads();
  if (t < 16) {
    int mm = t >> 3, bb = t & 7;
    float ss = 0.f;
    for (int c = 0; c < DK; ++c) ss += kern[mm * DK + c] * barL[bb * 128 + c];
    lgp[t] = ss;
  }
  __syncthreads();
  if (t < 16) {
    int mm = t >> 3;
    float mx = lgp[mm * 8];
    for (int i = 1; i < 8; ++i) mx = fmaxf(mx, lgp[mm * 8 + i]);
    exq[t] = __expf(lgp[t] - mx);
  }
  __syncthreads();
  if (t < 16) {
    int mm = t >> 3;
    float sm = 0.f;
    for (int i = 0; i < 8; ++i) sm += exq[mm * 8 + i];
    prp[t] = exq[t] / sm;  // flat[m*8+b]; read as [b*2+m] (TF reshape quirk)
  }
  __syncthreads();

  // ---- fold partner partial into live regs, normalize ----
  const float* pslot = slots + (size_t)pair * (2 * SLOTF) + (size_t)(kh ^ 1) * SLOTF;
  float rr[2];
#pragma unroll
  for (int su = 0; su < 2; ++su) {
    int r_ = (m * 128 + u * 32 + su * 16 + l16) * 128 + quad * 4;
#pragma unroll
    for (int cc = 0; cc < 8; ++cc) {
      f32x4 po = *(const f32x4*)(pslot + r_ + cc * 16);
#pragma unroll
      for (int e = 0; e < 4; ++e) acc[su][cc][e] += po[e];
    }
    float pl = pslot[32768 + m * 128 + u * 32 + su * 16 + l16];
    rr[su] = prp[b * 2 + m] / (lsum[su] + pl);
  }

  // ---- mix merge + store, two q-half passes (obuf holds 64 rows) ----
#pragma unroll
  for (int p = 0; p < 2; ++p) {
    __syncthreads();
    if ((u >> 1) == p && m == 0) {
#pragma unroll
      for (int su = 0; su < 2; ++su) {
        int r_ = ((u & 1) * 32 + su * 16 + l16) * 132 + quad * 4;
#pragma unroll
        for (int cc = 0; cc < 8; ++cc) {
          f32x4 o;
#pragma unroll
          for (int e = 0; e < 4; ++e) o[e] = acc[su][cc][e] * rr[su];
          *(f32x4*)&obuf[r_ + cc * 16] = o;
        }
      }
    }
    __syncthreads();
    if ((u >> 1) == p && m == 1) {
#pragma unroll
      for (int su = 0; su < 2; ++su) {
        int r_ = ((u & 1) * 32 + su * 16 + l16) * 132 + quad * 4;
#pragma unroll
        for (int cc = 0; cc < 8; ++cc) {
          f32x4 o = *(const f32x4*)&obuf[r_ + cc * 16];
#pragma unroll
          for (int e = 0; e < 4; ++e) o[e] += acc[su][cc][e] * rr[su];
          *(f32x4*)&obuf[r_ + cc * 16] = o;
        }
      }
    }
    __syncthreads();
    const int row = t >> 3;
    const int cb = (t & 7) * 16;
    float* op = out + ((size_t)b * NN + qb * 128 + p * 64 + row) * DK + cb;
#pragma unroll
    for (int g = 0; g < 4; ++g)
      *(f32x4*)(op + g * 4) = *(const f32x4*)&obuf[row * 132 + cb + g * 4];
  }
}

extern "C" void kernel_launch(void* const* d_in, const int* in_sizes, int n_in,
                              void* d_out, int out_size, void* d_ws, size_t ws_size,
                              hipStream_t stream) {
  const float* qt = (const float*)d_in[0];
  const float* kt = (const float*)d_in[1];
  const float* vt = (const float*)d_in[2];
  const float* kern = (const float*)d_in[3];
  float* out = (float*)d_out;

  char* ws = (char*)d_ws;
  int* counters = (int*)ws;                   // 128 ints (512 B, memset 0)
  float* qpart = (float*)(ws + 4096);         // 64*128 floats (32 KB)
  _Float16* khp = (_Float16*)(ws + 65536);    // 2M halfs (4 MB)
  _Float16* vTp = khp + (size_t)BS * NN * DK; // 2M halfs (4 MB)
  float* slots = (float*)(ws + (16u << 20));  // 128 pairs x 2 x SLOTF (~33 MB)

  hipMemsetAsync(counters, 0, 512, stream);
  prep_k<<<dim3(1088), dim3(256), 0, stream>>>(kt, khp, vt, vTp, qt, qpart);
  attn_k<<<dim3(256), dim3(512), 0, stream>>>(qt, khp, vTp, kern, qpart, slots,
                                              counters, out);
}

// Round 12
// 115.509 us; speedup vs baseline: 1.9054x; 1.6439x over previous
//
#include <hip/hip_runtime.h>
#include <hip/hip_fp16.h>

typedef float    f32x4 __attribute__((ext_vector_type(4)));
typedef _Float16 f16x2 __attribute__((ext_vector_type(2)));
typedef _Float16 f16x4 __attribute__((ext_vector_type(4)));
typedef _Float16 f16x8 __attribute__((ext_vector_type(8)));

#define BS 8
#define NN 2048
#define DK 128
#define DM 64
#define MIXOFF (1024 * DK)  // halfs between mix-0 and mix-1 rows of one batch
// log2(e) / sqrt(128): folds softmax temperature AND exp->exp2 conversion into Q
#define QSCALE 0.12751744116926208f

#define MFMA32(a, b, c) __builtin_amdgcn_mfma_f32_16x16x32_f16((a), (b), (c), 0, 0, 0)
#define EXP2(x) __builtin_amdgcn_exp2f(x)

__device__ __forceinline__ f16x2 pkrtz(float x, float y) {
  return __builtin_bit_cast(f16x2, __builtin_amdgcn_cvt_pkrtz(x, y));
}

// async global->LDS DMA, 16B per lane; no VGPR transit (allocator-proof)
__device__ __forceinline__ void load_lds16(const _Float16* g, _Float16* l) {
  __builtin_amdgcn_global_load_lds(
      (const __attribute__((address_space(1))) void*)(uintptr_t)g,
      (__attribute__((address_space(3))) void*)(uint32_t)(uintptr_t)l, 16, 0, 0);
}

// ---- fused prep: K f32->f16 (512 blk), V transpose 64x64 (512 blk), q-mean (64 blk) ----
__global__ void prep_k(const float* __restrict__ kt, _Float16* __restrict__ kh,
                       const float* __restrict__ vt, _Float16* __restrict__ vT,
                       const float* __restrict__ qt, float* __restrict__ qpart) {
  __shared__ float tile[64][65];
  __shared__ float red[256];
  int blk = blockIdx.x;
  int t = threadIdx.x;
  if (blk < 512) {
    size_t base = (size_t)blk * 4096;
#pragma unroll
    for (int j = 0; j < 4; ++j) {
      size_t i = base + j * 1024 + t * 4;
      f32x4 v = *(const f32x4*)(kt + i);
      f16x4 h;
      h[0] = (_Float16)v[0]; h[1] = (_Float16)v[1];
      h[2] = (_Float16)v[2]; h[3] = (_Float16)v[3];
      *(f16x4*)(kh + i) = h;
    }
  } else if (blk < 1024) {
    int i2 = blk - 512;
    int b = i2 >> 6;
    int rem = i2 & 63;
    int j0 = (rem & 31) * 64;   // key tile
    int c0 = (rem >> 5) * 64;   // channel tile
    int tx = t & 63, ty = t >> 6;
    const float* src = vt + ((size_t)b * NN + j0) * DK + c0;
#pragma unroll
    for (int rr = 0; rr < 16; ++rr) {
      int row = ty * 16 + rr;
      tile[row][tx] = src[(size_t)row * DK + tx];
    }
    __syncthreads();
    _Float16* dst = vT + ((size_t)b * DK + c0) * NN + j0;
    int chl = t >> 4;
    int k4 = (t & 15) * 4;
#pragma unroll
    for (int r2 = 0; r2 < 4; ++r2) {
      int ch = r2 * 16 + chl;
      f16x4 h;
      h[0] = (_Float16)tile[k4 + 0][ch]; h[1] = (_Float16)tile[k4 + 1][ch];
      h[2] = (_Float16)tile[k4 + 2][ch]; h[3] = (_Float16)tile[k4 + 3][ch];
      *(f16x4*)(dst + (size_t)ch * NN + k4) = h;
    }
  } else {
    int i = blk - 1024;
    int b = i >> 3, seg = i & 7;
    int c = t & 127, h = t >> 7;
    const float* p = qt + ((size_t)b * NN + seg * 256 + h * 128) * DK + c;
    float s = 0.f;
#pragma unroll 8
    for (int n = 0; n < 128; ++n) s += p[(size_t)n * DK];
    red[t] = s;
    __syncthreads();
    if (t < 128) qpart[(size_t)i * 128 + t] = red[t] + red[t + 128];
  }
}

// Stage step S for BOTH key halves (2 x 16KB) into buffer BUF. 2048 16B units,
// 512 threads x 4. Unit maps/swizzles verified in R6/R7/R8.
#define STAGE(BUF, S) do {                                                \
    _Float16* db_ = stg + (BUF) * 16384;                                  \
    load_lds16(khg + gKst + (S) * 2048, db_ + t * 8);                     \
    load_lds16(vTg + gVst + (S) * 32, db_ + 4096 + t * 8);                \
    load_lds16(khg + gKst + 65536 + (S) * 2048, db_ + 8192 + t * 8);      \
    load_lds16(vTg + gVst + 1024 + (S) * 32, db_ + 12288 + t * 8);        \
  } while (0)

// ---------------- main: mixture flash attention -------------------------------
// grid 256 x 512thr (1 blk/CU): b=blk&7, qb=blk>>3 (64 q/block).
// Wave = (m, kh, u): mix m, KEY-HALF kh (in-block split-K), q-tile u (32 q as
// 2 x 16q subtiles). Ratio 2.0 MFMA per ds_read_b128 (R8 was 1.0, LDS-bound):
// K frags (4 reads) -> 8 QK MFMAs; V frags (8 reads, shared by subtiles) -> 16
// PV. 32 steps (R8: 64) -> total LDS reads halve. Both kh tiles staged per step
// (32KB, dbuf 64KB static — R7-proven mechanics). kh merge via LDS in epilogue
// (4 sequential wave-group phases; R11's global-slot merge cost ~90us — never
// merge through global). l merged via small LDS buffer.
__global__ __launch_bounds__(512, 2) void attn_k(const float* __restrict__ qt,
                                                 const _Float16* __restrict__ khg,
                                                 const _Float16* __restrict__ vTg,
                                                 const float* __restrict__ kern,
                                                 const float* __restrict__ qpart,
                                                 float* __restrict__ out) {
  __shared__ __align__(16) char smem[65536];
  _Float16* stg = (_Float16*)smem;  // [2][16384] halfs = 2 x 32KB staging
  const int b = blockIdx.x & 7;
  const int qb = blockIdx.x >> 3;
  const int t = threadIdx.x;
  const int wv = t >> 6;
  const int m = wv >> 2;        // mixture
  const int kh = (wv >> 1) & 1; // key half (in-block split-K)
  const int u = wv & 1;         // 32-query tile
  const int lane = t & 63;
  const int quad = lane >> 4, l16 = lane & 15;
  const int perm = ((l16 >> 2) << 3) | (l16 & 3);
  const int bq = b * (NN * DK);
  const int bV = b * (DK * NN);

  // Q fragments: 2 subtiles x 2 chunks, f32 load + scale + pack in-register
  f16x8 qf[2][2];  // [su][chunk]
#pragma unroll
  for (int su = 0; su < 2; ++su)
#pragma unroll
    for (int c = 0; c < 2; ++c) {
      const float* qp_ = qt + bq + m * MIXOFF +
                         (qb * 64 + u * 32 + su * 16 + l16) * DM + quad * 8 + c * 32;
      f32x4 v0 = *(const f32x4*)qp_;
      f32x4 v1 = *(const f32x4*)(qp_ + 4);
      union { f16x8 v; f16x2 h[4]; } w;
      w.h[0] = pkrtz(v0[0] * QSCALE, v0[1] * QSCALE);
      w.h[1] = pkrtz(v0[2] * QSCALE, v0[3] * QSCALE);
      w.h[2] = pkrtz(v1[0] * QSCALE, v1[1] * QSCALE);
      w.h[3] = pkrtz(v1[2] * QSCALE, v1[3] * QSCALE);
      qf[su][c] = w.v;
    }

  // staging offsets (halfs): thread t stages K unit t / V unit t of each kh tile
  const int mixu = t >> 8;
  const int qq8 = t & 255;
  const int rK = qq8 >> 3;
  const int uuK = (qq8 & 7) ^ ((rK & 3) ^ ((rK >> 3) << 1));
  const int chV = t >> 2;
  const int uuV = (t & 3) ^ ((chV + (chV >> 2)) & 3);
  const int gKst = bq + mixu * MIXOFF + rK * 64 + uuK * 8;
  const int gVst = bV + chV * NN + uuV * 8;

  // LDS read offsets (halfs) within this wave's kh tile (verified maps)
  const int gK = (l16 & 3) ^ ((l16 >> 2) << 1);
  const int hV = (l16 + (l16 >> 2)) & 3;
  const int kA = (quad ^ gK) * 8;
  const int kB = ((quad + 4) ^ gK) * 8;
  const int kr0 = m * 2048 + perm * 64;
  const int kr1 = m * 2048 + (perm + 4) * 64;
  const int vbase = 4096 + l16 * 32 + (quad ^ hV) * 8;
  const int khoff = kh * 8192;

  const f32x4 z = {0.f, 0.f, 0.f, 0.f};
  f32x4 acc[2][8];  // [su][cc]
  float lsum[2] = {0.f, 0.f};
#pragma unroll
  for (int su = 0; su < 2; ++su)
#pragma unroll
    for (int cc = 0; cc < 8; ++cc) acc[su][cc] = z;

  STAGE(0, 0);
  int buf = 0;
  for (int s = 0; s < 32; ++s) {
    __syncthreads();  // tiles for step s landed; reads of buf^1 done
    if (s + 1 < 32) STAGE(buf ^ 1, s + 1);
    const _Float16* sb_ = stg + buf * 16384 + khoff;
    f16x8 kf0 = *(const f16x8*)(sb_ + kr0 + kA);
    f16x8 kf1 = *(const f16x8*)(sb_ + kr0 + kB);
    f16x8 kf2 = *(const f16x8*)(sb_ + kr1 + kA);
    f16x8 kf3 = *(const f16x8*)(sb_ + kr1 + kB);
    f16x8 vf[8];
#pragma unroll
    for (int cc = 0; cc < 8; ++cc) vf[cc] = *(const f16x8*)(sb_ + vbase + cc * 512);
#pragma unroll
    for (int su = 0; su < 2; ++su) {
      f32x4 s0 = MFMA32(kf1, qf[su][1], MFMA32(kf0, qf[su][0], z));
      f32x4 s1 = MFMA32(kf3, qf[su][1], MFMA32(kf2, qf[su][0], z));
      float e0 = EXP2(s0[0]), e1 = EXP2(s0[1]), e2 = EXP2(s0[2]), e3 = EXP2(s0[3]);
      float e4 = EXP2(s1[0]), e5 = EXP2(s1[1]), e6 = EXP2(s1[2]), e7 = EXP2(s1[3]);
      lsum[su] += ((e0 + e1) + (e2 + e3)) + ((e4 + e5) + (e6 + e7));
      union { f16x8 v; f16x2 h[4]; } w;
      w.h[0] = pkrtz(e0, e1); w.h[1] = pkrtz(e2, e3);
      w.h[2] = pkrtz(e4, e5); w.h[3] = pkrtz(e6, e7);
#pragma unroll
      for (int cc = 0; cc < 8; ++cc) acc[su][cc] = MFMA32(vf[cc], w.v, acc[su][cc]);
    }
    buf ^= 1;
  }
  __syncthreads();  // all tile reads done; epilogue overlays staging LDS

  // ---- epilogue LDS overlay ----
  float* obuf = (float*)smem;                  // [64][132] floats (33792 B)
  float* barL = (float*)(smem + 33792);        // [8][128]
  float* lgp = (float*)(smem + 37888);
  float* exq = (float*)(smem + 37952);
  float* prp = (float*)(smem + 38016);
  float* lbuf = (float*)(smem + 38144);        // [2][64]: l merged over kh

  // l: reduce across quads, then merge kh halves via lbuf
#pragma unroll
  for (int su = 0; su < 2; ++su) {
    lsum[su] += __shfl_xor(lsum[su], 16);
    lsum[su] += __shfl_xor(lsum[su], 32);
  }
  // prior softmax inputs (redundant per block) — interleave with l merge
  for (int e = t; e < 1024; e += 512) {
    int bb = e >> 7, c = e & 127;
    float ss = 0.f;
#pragma unroll
    for (int seg = 0; seg < 8; ++seg) ss += qpart[(size_t)(bb * 8 + seg) * 128 + c];
    barL[e] = ss * (1.0f / 2048.0f);
  }
  if (kh == 0 && quad == 0)
#pragma unroll
    for (int su = 0; su < 2; ++su) lbuf[m * 64 + u * 32 + su * 16 + l16] = lsum[su];
  __syncthreads();
  if (kh == 1 && quad == 0)
#pragma unroll
    for (int su = 0; su < 2; ++su) lbuf[m * 64 + u * 32 + su * 16 + l16] += lsum[su];
  if (t < 16) {
    int mm = t >> 3, bb = t & 7;
    float ss = 0.f;
    for (int c = 0; c < DK; ++c) ss += kern[mm * DK + c] * barL[bb * 128 + c];
    lgp[t] = ss;
  }
  __syncthreads();
  if (t < 16) {
    int mm = t >> 3;
    float mx = lgp[mm * 8];
    for (int i = 1; i < 8; ++i) mx = fmaxf(mx, lgp[mm * 8 + i]);
    exq[t] = __expf(lgp[t] - mx);
  }
  __syncthreads();
  if (t < 16) {
    int mm = t >> 3;
    float sm = 0.f;
    for (int i = 0; i < 8; ++i) sm += exq[mm * 8 + i];
    prp[t] = exq[t] / sm;  // flat[m*8+b]; read as [b*2+m] (TF reshape quirk)
  }
  __syncthreads();

  const float wm = prp[b * 2 + m];
  float rr[2];
#pragma unroll
  for (int su = 0; su < 2; ++su)
    rr[su] = wm / lbuf[m * 64 + u * 32 + su * 16 + l16];

  // ---- 4-phase LDS merge: obuf = (m0kh0 + m0kh1)*r0 + m1kh0*r1 + m1kh1*r1 ----
  // phase 1: m0,kh0 waves seed with raw acc
  if (m == 0 && kh == 0) {
#pragma unroll
    for (int su = 0; su < 2; ++su) {
      int r_ = (u * 32 + su * 16 + l16) * 132 + quad * 4;
#pragma unroll
      for (int cc = 0; cc < 8; ++cc) *(f32x4*)&obuf[r_ + cc * 16] = acc[su][cc];
    }
  }
  __syncthreads();
  // phase 2: m0,kh1 waves add + scale by r0 (same r for both kh: l already merged)
  if (m == 0 && kh == 1) {
#pragma unroll
    for (int su = 0; su < 2; ++su) {
      int r_ = (u * 32 + su * 16 + l16) * 132 + quad * 4;
#pragma unroll
      for (int cc = 0; cc < 8; ++cc) {
        f32x4 o = *(const f32x4*)&obuf[r_ + cc * 16];
#pragma unroll
        for (int e = 0; e < 4; ++e) o[e] = (o[e] + acc[su][cc][e]) * rr[su];
        *(f32x4*)&obuf[r_ + cc * 16] = o;
      }
    }
  }
  __syncthreads();
  // phase 3: m1,kh0 += acc*r1
  if (m == 1 && kh == 0) {
#pragma unroll
    for (int su = 0; su < 2; ++su) {
      int r_ = (u * 32 + su * 16 + l16) * 132 + quad * 4;
#pragma unroll
      for (int cc = 0; cc < 8; ++cc) {
        f32x4 o = *(const f32x4*)&obuf[r_ + cc * 16];
#pragma unroll
        for (int e = 0; e < 4; ++e) o[e] += acc[su][cc][e] * rr[su];
        *(f32x4*)&obuf[r_ + cc * 16] = o;
      }
    }
  }
  __syncthreads();
  // phase 4: m1,kh1 += acc*r1
  if (m == 1 && kh == 1) {
#pragma unroll
    for (int su = 0; su < 2; ++su) {
      int r_ = (u * 32 + su * 16 + l16) * 132 + quad * 4;
#pragma unroll
      for (int cc = 0; cc < 8; ++cc) {
        f32x4 o = *(const f32x4*)&obuf[r_ + cc * 16];
#pragma unroll
        for (int e = 0; e < 4; ++e) o[e] += acc[su][cc][e] * rr[su];
        *(f32x4*)&obuf[r_ + cc * 16] = o;
      }
    }
  }
  __syncthreads();
  const int row = t >> 3;
  const int cb = (t & 7) * 16;
  float* op = out + ((size_t)b * NN + qb * 64 + row) * DK + cb;
#pragma unroll
  for (int g = 0; g < 4; ++g)
    *(f32x4*)(op + g * 4) = *(const f32x4*)&obuf[row * 132 + cb + g * 4];
}

extern "C" void kernel_launch(void* const* d_in, const int* in_sizes, int n_in,
                              void* d_out, int out_size, void* d_ws, size_t ws_size,
                              hipStream_t stream) {
  const float* qt = (const float*)d_in[0];
  const float* kt = (const float*)d_in[1];
  const float* vt = (const float*)d_in[2];
  const float* kern = (const float*)d_in[3];
  float* out = (float*)d_out;

  char* ws = (char*)d_ws;
  float* qpart = (float*)(ws + 4096);         // 64*128 floats (32 KB)
  _Float16* khp = (_Float16*)(ws + 65536);    // 2M halfs (4 MB)
  _Float16* vTp = khp + (size_t)BS * NN * DK; // 2M halfs (4 MB)

  prep_k<<<dim3(1088), dim3(256), 0, stream>>>(kt, khp, vt, vTp, qt, qpart);
  attn_k<<<dim3(256), dim3(512), 0, stream>>>(qt, khp, vTp, kern, qpart, out);
}